// Round 1
// baseline (182.386 us; speedup 1.0000x reference)
//
#include <hip/hip_runtime.h>

#define N_ROWS 65536
#define K_CL   1024
#define D_DIM  256
#define A_DIM  64

typedef float f32x4 __attribute__((ext_vector_type(4)));
typedef short s16x8 __attribute__((ext_vector_type(8)));

__device__ __forceinline__ unsigned short f2bf(float f) {
    unsigned u = __builtin_bit_cast(unsigned, f);
    u += 0x7FFFu + ((u >> 16) & 1u);
    return (unsigned short)(u >> 16);
}
__device__ __forceinline__ float bf2f(unsigned short h) {
    unsigned u = ((unsigned)h) << 16;
    return __builtin_bit_cast(float, u);
}

// Fused: dist-GEMM (bf16 MFMA) -> w = |cw|*exp(-t*dist) -> rowsum -> (w@means)/(sum+1)
// 256 threads = 4 waves; each wave owns 32 rows (2 M-subtiles of 16).
// LDS region (64 KB) is time-shared: phase A = s tile bf16 [128][256] (swizzled);
// phase B = centers chunk bf16 [64][256] (swizzled) + means f32 [64][64] + E bf16 [4][32][64].
__global__ __launch_bounds__(256, 2)
void fused_mean_kernel(const float* __restrict__ s,
                       const float* __restrict__ centers,
                       const float* __restrict__ cw,
                       const float* __restrict__ means,
                       const float* __restrict__ log_temp,
                       float* __restrict__ out)
{
    __shared__ __align__(16) char smem[65536];
    __shared__ float sn2[128];
    __shared__ float cn2[64];
    __shared__ float aww[64];
    __shared__ float rsl[4][32];

    const int tid  = threadIdx.x;
    const int lane = tid & 63;
    const int wid  = tid >> 6;
    const int lo   = lane & 15;
    const int hi   = lane >> 4;
    const long brow0 = (long)blockIdx.x * 128;

    const float temp = __expf(log_temp[0]);
    const float te   = temp * 1.44269504088896340736f;  // temp * log2(e), for exp2
    const float t2e  = 2.0f * te;

    // ---------------- stage s tile: f32 global -> bf16 LDS (XOR-swizzled) + sn2 ----------------
    for (int i = 0; i < 32; ++i) {
        const int row = 4 * i + wid;                         // 0..127, uniform per wave
        const float4 v = ((const float4*)(s + (brow0 + row) * D_DIM))[lane];
        float ss = v.x * v.x + v.y * v.y + v.z * v.z + v.w * v.w;
        #pragma unroll
        for (int m = 1; m < 64; m <<= 1) ss += __shfl_xor(ss, m, 64);
        if (lane == 0) sn2[row] = ss;
        const int cb = (lane * 8) ^ ((row & 7) << 4);        // 8B store, swizzled within row
        unsigned long long p = (unsigned long long)f2bf(v.x)
                             | ((unsigned long long)f2bf(v.y) << 16)
                             | ((unsigned long long)f2bf(v.z) << 32)
                             | ((unsigned long long)f2bf(v.w) << 48);
        *(unsigned long long*)(smem + row * 512 + cb) = p;
    }
    __syncthreads();

    // ---------------- extract A fragments (held in registers for the whole K-loop) ----------------
    s16x8 afrag[2][8];
    #pragma unroll
    for (int m = 0; m < 2; ++m)
        #pragma unroll
        for (int ks = 0; ks < 8; ++ks) {
            const int row = wid * 32 + m * 16 + lo;          // A-frag row = lane&15
            const int cb  = (ks * 64 + hi * 16) ^ ((row & 7) << 4);
            afrag[m][ks] = *(const s16x8*)(smem + row * 512 + cb);
        }
    float a1[2][4];                                           // -te * ||s_row||^2 (C-layout rows)
    #pragma unroll
    for (int m = 0; m < 2; ++m)
        #pragma unroll
        for (int r = 0; r < 4; ++r)
            a1[m][r] = -te * sn2[wid * 32 + m * 16 + hi * 4 + r];
    __syncthreads();   // before centers chunk overwrites the s region

    unsigned short* const Ebuf = (unsigned short*)(smem + 49152) + wid * 2048; // [32][64] bf16 per wave
    float* const mlds = (float*)(smem + 32768);                                 // [64][64] f32

    float accpv[32];
    #pragma unroll
    for (int r = 0; r < 32; ++r) accpv[r] = 0.0f;
    float rs[2][4] = {};

    for (int c = 0; c < 16; ++c) {
        // ---- stage centers chunk (f32 -> bf16, swizzled) + cn2 ----
        for (int i = 0; i < 16; ++i) {
            const int row = 4 * i + wid;                     // 0..63, uniform per wave
            const float4 v = ((const float4*)(centers + (long)(c * 64 + row) * D_DIM))[lane];
            float ss = v.x * v.x + v.y * v.y + v.z * v.z + v.w * v.w;
            #pragma unroll
            for (int m = 1; m < 64; m <<= 1) ss += __shfl_xor(ss, m, 64);
            if (lane == 0) cn2[row] = ss;
            const int cb = (lane * 8) ^ ((row & 7) << 4);
            unsigned long long p = (unsigned long long)f2bf(v.x)
                                 | ((unsigned long long)f2bf(v.y) << 16)
                                 | ((unsigned long long)f2bf(v.z) << 32)
                                 | ((unsigned long long)f2bf(v.w) << 48);
            *(unsigned long long*)(smem + row * 512 + cb) = p;
        }
        // ---- stage means chunk (kept f32, only read in rare fallback) ----
        #pragma unroll
        for (int i = 0; i < 4; ++i) {
            const int idx = tid + 256 * i;
            const int row = idx >> 4, c4 = idx & 15;
            const float4 v = ((const float4*)(means + (long)(c * 64 + row) * A_DIM))[c4];
            ((float4*)(mlds + row * 64))[c4] = v;
        }
        if (tid < 64) aww[tid] = fabsf(cw[c * 64 + tid]);
        __syncthreads();

        // ---- MFMA: dots = s_rows . centers_rows  (per wave: 32 rows x 64 clusters) ----
        f32x4 acc[2][4] = {};
        #pragma unroll
        for (int ks = 0; ks < 8; ++ks) {
            s16x8 b[4];
            #pragma unroll
            for (int t = 0; t < 4; ++t) {
                const int cl = t * 16 + lo;                  // B-frag col = lane&15
                const int cb = (ks * 64 + hi * 16) ^ ((cl & 7) << 4);
                b[t] = *(const s16x8*)(smem + cl * 512 + cb);
            }
            #pragma unroll
            for (int m = 0; m < 2; ++m)
                #pragma unroll
                for (int t = 0; t < 4; ++t)
                    acc[m][t] = __builtin_amdgcn_mfma_f32_16x16x32_bf16(afrag[m][ks], b[t], acc[m][t], 0, 0, 0);
        }

        // ---- epilogue: w = |cw| * exp2(-te*(sn2+cn2) + 2te*dot); rowsum; skip-or-fallback PV ----
        bool nz = false;
        #pragma unroll
        for (int t = 0; t < 4; ++t) {
            const int col = t * 16 + lo;
            const float ca  = -te * cn2[col];
            const float caw = aww[col];
            #pragma unroll
            for (int m = 0; m < 2; ++m)
                #pragma unroll
                for (int r = 0; r < 4; ++r) {
                    const float arg = fmaf(t2e, acc[m][t][r], ca + a1[m][r]);
                    const float w = caw * exp2f(arg);
                    rs[m][r] += w;
                    nz |= (w != 0.0f);
                }
        }
        // Exact sparsity skip: if every w in this wave's 32x64 chunk is +0.0f, the PV
        // contribution is exactly zero -> skip. Otherwise run the exact fallback.
        if (__ballot(nz) != 0ULL) {
            #pragma unroll
            for (int t = 0; t < 4; ++t) {
                const int col = t * 16 + lo;
                const float ca  = -te * cn2[col];
                const float caw = aww[col];
                #pragma unroll
                for (int m = 0; m < 2; ++m)
                    #pragma unroll
                    for (int r = 0; r < 4; ++r) {
                        const float arg = fmaf(t2e, acc[m][t][r], ca + a1[m][r]);
                        const float w = caw * exp2f(arg);
                        Ebuf[(m * 16 + hi * 4 + r) * 64 + col] = f2bf(w);
                    }
            }
            __threadfence_block();   // intra-wave LDS visibility; no barrier (divergent-safe)
            for (int k = 0; k < 64; ++k) {
                const float mv = mlds[k * 64 + lane];        // lane == output column a
                #pragma unroll
                for (int r2 = 0; r2 < 32; ++r2)
                    accpv[r2] += bf2f(Ebuf[r2 * 64 + k]) * mv;
            }
        }
        __syncthreads();
    }

    // ---- rowsum reduce across the 16 column-lanes, then normalize & write ----
    #pragma unroll
    for (int m = 0; m < 2; ++m)
        #pragma unroll
        for (int r = 0; r < 4; ++r) {
            float v = rs[m][r];
            #pragma unroll
            for (int d = 1; d < 16; d <<= 1) v += __shfl_xor(v, d, 64);
            rs[m][r] = v;
        }
    if (lo == 0) {
        #pragma unroll
        for (int m = 0; m < 2; ++m)
            #pragma unroll
            for (int r = 0; r < 4; ++r)
                rsl[wid][m * 16 + hi * 4 + r] = rs[m][r];
    }
    __syncthreads();
    #pragma unroll
    for (int r2 = 0; r2 < 32; ++r2) {
        const float denom = rsl[wid][r2] + 1.0f;
        const long grow = brow0 + wid * 32 + r2;
        out[grow * A_DIM + lane] = accpv[r2] / denom;        // coalesced 64-wide row store
    }
}

__global__ void chol_kernel(const float* __restrict__ log_sigma, float* __restrict__ out2)
{
    const int i = blockIdx.x * 256 + threadIdx.x;            // < 4096
    const int r = i >> 6, c = i & 63;
    out2[i] = (r == c) ? __expf(log_sigma[r]) : 0.0f;
}

extern "C" void kernel_launch(void* const* d_in, const int* in_sizes, int n_in,
                              void* d_out, int out_size, void* d_ws, size_t ws_size,
                              hipStream_t stream)
{
    const float* s       = (const float*)d_in[0];
    const float* centers = (const float*)d_in[1];
    const float* cwts    = (const float*)d_in[2];
    const float* means   = (const float*)d_in[3];
    const float* lsig    = (const float*)d_in[4];
    const float* ltemp   = (const float*)d_in[5];
    float* out = (float*)d_out;

    fused_mean_kernel<<<N_ROWS / 128, 256, 0, stream>>>(s, centers, cwts, means, ltemp, out);
    chol_kernel<<<(A_DIM * A_DIM) / 256, 256, 0, stream>>>(lsig, out + (long)N_ROWS * A_DIM);
}

// Round 2
// 72.101 us; speedup vs baseline: 2.5296x; 2.5296x over previous
//
#include <hip/hip_runtime.h>

#define N_ROWS 65536
#define K_CL   1024
#define D_DIM  256
#define A_DIM  64
#define CHUNK  32              // clusters per chunk
#define NCH    (K_CL / CHUNK)  // 32 chunks

// d_ws layout: [0, 512K): centers bf16, row pitch 512B, XOR-swizzled
//              [512K, 516K): cn2[1024] f32   [516K, 520K): |cw|[1024] f32
#define WS_C_BYTES (K_CL * 512)
#define WS_CN2_OFF WS_C_BYTES
#define WS_AW_OFF  (WS_C_BYTES + K_CL * 4)

typedef float f32x4 __attribute__((ext_vector_type(4)));
typedef short s16x8 __attribute__((ext_vector_type(8)));

__device__ __forceinline__ unsigned short f2bf(float f) {
    unsigned u = __builtin_bit_cast(unsigned, f);
    u += 0x7FFFu + ((u >> 16) & 1u);
    return (unsigned short)(u >> 16);
}

// ---------------- prep: centers -> bf16 pre-swizzled + cn2 + |cw| ----------------
__global__ __launch_bounds__(256) void prep_kernel(const float* __restrict__ centers,
                                                   const float* __restrict__ cw,
                                                   unsigned char* __restrict__ ws)
{
    const int tid = threadIdx.x, lane = tid & 63, wid = tid >> 6;
    #pragma unroll
    for (int i = 0; i < 4; ++i) {
        const int row = blockIdx.x * 16 + wid * 4 + i;   // 0..1023
        const float4 v = ((const float4*)(centers + (long)row * D_DIM))[lane];
        float ss = v.x * v.x + v.y * v.y + v.z * v.z + v.w * v.w;
        #pragma unroll
        for (int m = 1; m < 64; m <<= 1) ss += __shfl_xor(ss, m, 64);
        if (lane == 0) ((float*)(ws + WS_CN2_OFF))[row] = ss;
        const int off = (lane * 8) ^ ((row & 7) << 4);   // pre-swizzle within row
        unsigned long long p = (unsigned long long)f2bf(v.x)
                             | ((unsigned long long)f2bf(v.y) << 16)
                             | ((unsigned long long)f2bf(v.z) << 32)
                             | ((unsigned long long)f2bf(v.w) << 48);
        *(unsigned long long*)(ws + (long)row * 512 + off) = p;
    }
    const int idx = blockIdx.x * 256 + tid;
    if (idx < K_CL) ((float*)(ws + WS_AW_OFF))[idx] = fabsf(cw[idx]);
}

// ---------------- slow exact fallback (block-uniform, never taken for these inputs) ----------------
__device__ __attribute__((noinline))
void slow_path(const float* s, const float* centers, const float* cw, const float* means,
               float temp, long brow0, int wid, int lane, float* out)
{
    for (int r2 = 0; r2 < 32; ++r2) {
        const long row = brow0 + wid * 32 + r2;
        const float4 sv = ((const float4*)(s + row * D_DIM))[lane];
        float acc_a = 0.f, rsum = 0.f;
        for (int k = 0; k < K_CL; ++k) {
            const float4 cv = ((const float4*)(centers + (long)k * D_DIM))[lane];
            float d2 = (sv.x - cv.x) * (sv.x - cv.x) + (sv.y - cv.y) * (sv.y - cv.y)
                     + (sv.z - cv.z) * (sv.z - cv.z) + (sv.w - cv.w) * (sv.w - cv.w);
            #pragma unroll
            for (int m = 1; m < 64; m <<= 1) d2 += __shfl_xor(d2, m, 64);
            const float w = fabsf(cw[k]) * __expf(-temp * d2);
            rsum += w;
            acc_a += w * means[k * A_DIM + lane];
        }
        out[row * A_DIM + lane] = acc_a / (rsum + 1.f);
    }
}

// ---------------- main fused kernel ----------------
// 256 thr = 4 waves, 128 rows/block, Mwave=32. LDS region0 (64KB) time-shared:
// phase A = s tile bf16 [128][512B] swizzled; phase B = 3x16KB center-chunk ring.
// region1 (8KB) = cn2 + |cw| tables. Counted-vmcnt 3-deep pipeline, raw s_barrier.
__global__ __launch_bounds__(256, 2)
void fused_kernel(const float* __restrict__ s,
                  const unsigned char* __restrict__ ws,
                  const float* __restrict__ means,
                  const float* __restrict__ centers,
                  const float* __restrict__ cw,
                  const float* __restrict__ log_temp,
                  float* __restrict__ out)
{
    __shared__ __align__(16) unsigned char smem[65536 + 8192];
    __shared__ float sn2[128];
    __shared__ int nzflags[4];

    const int tid  = threadIdx.x;
    const int lane = tid & 63;
    const int wid  = tid >> 6;
    const int lo   = lane & 15;
    const int hi   = lane >> 4;
    const long brow0 = (long)blockIdx.x * 128;

    const float temp = __expf(log_temp[0]);
    const float te   = temp * 1.44269504088896340736f;
    const float t2e  = 2.0f * te;

    // preload cn2 + |cw| tables (8KB contiguous in ws)
    {
        const f32x4* src = (const f32x4*)(ws + WS_CN2_OFF);
        f32x4* dst = (f32x4*)(smem + 65536);
        #pragma unroll
        for (int i = 0; i < 2; ++i) dst[tid + 256 * i] = src[tid + 256 * i];
    }

    // stage s tile: f32 -> bf16 LDS (swizzled) + sn2
    for (int i = 0; i < 32; ++i) {
        const int row = 4 * i + wid;
        const float4 v = ((const float4*)(s + (brow0 + row) * D_DIM))[lane];
        float ss = v.x * v.x + v.y * v.y + v.z * v.z + v.w * v.w;
        #pragma unroll
        for (int m = 1; m < 64; m <<= 1) ss += __shfl_xor(ss, m, 64);
        if (lane == 0) sn2[row] = ss;
        const int cb = (lane * 8) ^ ((row & 7) << 4);
        unsigned long long p = (unsigned long long)f2bf(v.x)
                             | ((unsigned long long)f2bf(v.y) << 16)
                             | ((unsigned long long)f2bf(v.z) << 32)
                             | ((unsigned long long)f2bf(v.w) << 48);
        *(unsigned long long*)(smem + row * 512 + cb) = p;
    }
    __syncthreads();

    // extract A fragments (registers for the whole K loop)
    s16x8 afrag[2][8];
    #pragma unroll
    for (int m = 0; m < 2; ++m)
        #pragma unroll
        for (int ks = 0; ks < 8; ++ks) {
            const int row = wid * 32 + m * 16 + lo;
            const int cb  = (ks * 64 + hi * 16) ^ ((row & 7) << 4);
            afrag[m][ks] = *(const s16x8*)(smem + row * 512 + cb);
        }
    float a1[2][4];
    #pragma unroll
    for (int m = 0; m < 2; ++m)
        #pragma unroll
        for (int r = 0; r < 4; ++r)
            a1[m][r] = -te * sn2[wid * 32 + m * 16 + hi * 4 + r];
    __syncthreads();   // region0 free; also drains vmcnt to 0

    const float* cn2a = (const float*)(smem + 65536);
    const float* awa  = cn2a + K_CL;

    // stage one 16KB chunk (pre-swizzled bf16) via global_load_lds: 4 issues/thread
#define STAGE(bufi, chunk) do {                                                        \
        const unsigned char* _g = ws + (chunk) * (CHUNK * 512) + wid * 1024 + (lane << 4); \
        unsigned char* _l = (unsigned char*)smem + (bufi) * 16384 + wid * 1024;        \
        _Pragma("unroll")                                                              \
        for (int _i = 0; _i < 4; ++_i) {                                               \
            __builtin_amdgcn_global_load_lds(                                          \
                (const __attribute__((address_space(1))) unsigned int*)(_g + _i * 4096), \
                (__attribute__((address_space(3))) unsigned int*)(_l + _i * 4096),     \
                16, 0, 0);                                                             \
        }                                                                              \
    } while (0)

    STAGE(0, 0);
    STAGE(1, 1);

    float rssum = 0.f;

    for (int c = 0; c < NCH; ++c) {
        const int p = c % 3;
        if (c + 2 < NCH) STAGE((c + 2) % 3, c + 2);
        // wait for chunk c's 4 loads (keep the younger 8 in flight)
        if (c < NCH - 2)       asm volatile("s_waitcnt vmcnt(8)" ::: "memory");
        else if (c == NCH - 2) asm volatile("s_waitcnt vmcnt(4)" ::: "memory");
        else                   asm volatile("s_waitcnt vmcnt(0)" ::: "memory");
        __builtin_amdgcn_s_barrier();
        __builtin_amdgcn_sched_barrier(0);

        const unsigned char* bb = smem + p * 16384;
        f32x4 acc[2][2] = {};
        #pragma unroll
        for (int ks = 0; ks < 8; ++ks) {
            s16x8 b[2];
            #pragma unroll
            for (int t = 0; t < 2; ++t) {
                const int cl = t * 16 + lo;
                const int cb = (ks * 64 + hi * 16) ^ ((cl & 7) << 4);
                b[t] = *(const s16x8*)(bb + cl * 512 + cb);
            }
            #pragma unroll
            for (int m = 0; m < 2; ++m)
                #pragma unroll
                for (int t = 0; t < 2; ++t)
                    acc[m][t] = __builtin_amdgcn_mfma_f32_16x16x32_bf16(afrag[m][ks], b[t], acc[m][t], 0, 0, 0);
        }

        // epilogue: w = |cw| * exp2(t2e*dot - te*(cn2+sn2)); w>=0, so sum==0 <=> all zero
        #pragma unroll
        for (int t = 0; t < 2; ++t) {
            const int col = c * CHUNK + t * 16 + lo;
            const float ca  = -te * cn2a[col];
            const float caw = awa[col];
            #pragma unroll
            for (int m = 0; m < 2; ++m)
                #pragma unroll
                for (int r = 0; r < 4; ++r) {
                    const float arg = fmaf(t2e, acc[m][t][r], ca + a1[m][r]);
                    rssum += caw * exp2f(arg);
                }
        }
        __builtin_amdgcn_s_barrier();   // all waves done reading buf[p] before it is re-staged
    }
#undef STAGE

    // block-wide exactness check: any nonzero w anywhere?
    const unsigned long long bal = __ballot(rssum != 0.f);
    if (lane == 0) nzflags[wid] = (bal != 0ULL) ? 1 : 0;
    __syncthreads();
    const int nzany = nzflags[0] | nzflags[1] | nzflags[2] | nzflags[3];

    if (nzany) {
        slow_path(s, centers, cw, means, temp, brow0, wid, lane, out);
    } else {
        // numerator exactly 0 for every row -> out = 0/(0+1) = 0
        const float4 z = {0.f, 0.f, 0.f, 0.f};
        float4* ob = (float4*)(out + (brow0 + wid * 32) * A_DIM);
        #pragma unroll
        for (int i = 0; i < 8; ++i) ob[lane + 64 * i] = z;
    }
}

__global__ void chol_kernel(const float* __restrict__ log_sigma, float* __restrict__ out2)
{
    const int i = blockIdx.x * 256 + threadIdx.x;   // < 4096
    const int r = i >> 6, c = i & 63;
    out2[i] = (r == c) ? __expf(log_sigma[r]) : 0.0f;
}

extern "C" void kernel_launch(void* const* d_in, const int* in_sizes, int n_in,
                              void* d_out, int out_size, void* d_ws, size_t ws_size,
                              hipStream_t stream)
{
    const float* s       = (const float*)d_in[0];
    const float* centers = (const float*)d_in[1];
    const float* cwts    = (const float*)d_in[2];
    const float* means   = (const float*)d_in[3];
    const float* lsig    = (const float*)d_in[4];
    const float* ltemp   = (const float*)d_in[5];
    float* out = (float*)d_out;
    unsigned char* ws = (unsigned char*)d_ws;   // needs 520KB

    prep_kernel<<<64, 256, 0, stream>>>(centers, cwts, ws);
    fused_kernel<<<N_ROWS / 128, 256, 0, stream>>>(s, ws, means, centers, cwts, ltemp, out);
    chol_kernel<<<(A_DIM * A_DIM) / 256, 256, 0, stream>>>(lsig, out + (long)N_ROWS * A_DIM);
}

// Round 3
// 63.183 us; speedup vs baseline: 2.8867x; 1.1412x over previous
//
#include <hip/hip_runtime.h>

#define N_ROWS 65536
#define K_CL   1024
#define D_DIM  256
#define A_DIM  64
#define CHUNK  32              // clusters per chunk
#define NCH    (K_CL / CHUNK)  // 32 chunks
#define RB     16384           // ring buffer stride (32 rows x 512B)

// d_ws layout: [0, 512K): centers bf16, row pitch 512B, XOR-swizzled
//              [512K, 516K): q[1024] f32 = -te*cn2 + log2|cw|
#define WS_Q_OFF (K_CL * 512)

typedef float f32x4 __attribute__((ext_vector_type(4)));
typedef short s16x8 __attribute__((ext_vector_type(8)));

__device__ __forceinline__ unsigned short f2bf(float f) {
    unsigned u = __builtin_bit_cast(unsigned, f);
    u += 0x7FFFu + ((u >> 16) & 1u);
    return (unsigned short)(u >> 16);
}

// ---------------- prep: centers -> bf16 pre-swizzled + q table ----------------
__global__ __launch_bounds__(256) void prep_kernel(const float* __restrict__ centers,
                                                   const float* __restrict__ cw,
                                                   const float* __restrict__ log_temp,
                                                   unsigned char* __restrict__ ws)
{
    const int tid = threadIdx.x, lane = tid & 63, wid = tid >> 6;
    const float te = __expf(log_temp[0]) * 1.44269504088896340736f;
    #pragma unroll
    for (int i = 0; i < 4; ++i) {
        const int row = blockIdx.x * 16 + wid * 4 + i;   // 0..1023
        const float4 v = ((const float4*)(centers + (long)row * D_DIM))[lane];
        float ss = v.x * v.x + v.y * v.y + v.z * v.z + v.w * v.w;
        #pragma unroll
        for (int m = 1; m < 64; m <<= 1) ss += __shfl_xor(ss, m, 64);
        if (lane == 0)
            ((float*)(ws + WS_Q_OFF))[row] = fmaf(-te, ss, __log2f(fabsf(cw[row])));
        const int off = (lane * 8) ^ ((row & 7) << 4);   // pre-swizzle within row
        unsigned long long p = (unsigned long long)f2bf(v.x)
                             | ((unsigned long long)f2bf(v.y) << 16)
                             | ((unsigned long long)f2bf(v.z) << 32)
                             | ((unsigned long long)f2bf(v.w) << 48);
        *(unsigned long long*)(ws + (long)row * 512 + off) = p;
    }
}

// ---------------- slow exact fallback (block-uniform, never taken for these inputs) ----------------
__device__ __attribute__((noinline))
void slow_path(const float* s, const float* centers, const float* cw, const float* means,
               float temp, long brow0, int wid, int lane, float* out)
{
    for (int r2 = 0; r2 < 32; ++r2) {
        const long row = brow0 + wid * 32 + r2;
        const float4 sv = ((const float4*)(s + row * D_DIM))[lane];
        float acc_a = 0.f, rsum = 0.f;
        for (int k = 0; k < K_CL; ++k) {
            const float4 cv = ((const float4*)(centers + (long)k * D_DIM))[lane];
            float d2 = (sv.x - cv.x) * (sv.x - cv.x) + (sv.y - cv.y) * (sv.y - cv.y)
                     + (sv.z - cv.z) * (sv.z - cv.z) + (sv.w - cv.w) * (sv.w - cv.w);
            #pragma unroll
            for (int m = 1; m < 64; m <<= 1) d2 += __shfl_xor(d2, m, 64);
            const float w = fabsf(cw[k]) * __expf(-temp * d2);
            rsum += w;
            acc_a += w * means[k * A_DIM + lane];
        }
        out[row * A_DIM + lane] = acc_a / (rsum + 1.f);
    }
}

// ---------------- main fused kernel ----------------
// 256 thr = 4 waves, 128 rows/block, Mwave=32. LDS: 4x16KB ring (time-shared with
// the 64KB s-tile in the prologue) + 4KB q table. Single barrier per chunk,
// 2-chunk prefetch via counted vmcnt(8), all ds_read addresses = 2 VGPRs + imm.
__global__ __launch_bounds__(256, 2)
void fused_kernel(const float* __restrict__ s,
                  const unsigned char* __restrict__ ws,
                  const float* __restrict__ means,
                  const float* __restrict__ centers,
                  const float* __restrict__ cw,
                  const float* __restrict__ log_temp,
                  float* __restrict__ out)
{
    __shared__ __align__(16) unsigned char smem[4 * RB + 4096];
    __shared__ float sn2[128];
    __shared__ int nzflags[4];

    const int tid  = threadIdx.x;
    const int lane = tid & 63;
    const int wid  = tid >> 6;
    const int lo   = lane & 15;
    const int hi   = lane >> 4;
    const long brow0 = (long)blockIdx.x * 128;

    const float temp = __expf(log_temp[0]);
    const float te   = temp * 1.44269504088896340736f;
    const float t2e  = 2.0f * te;

    // preload q table (4KB)
    ((f32x4*)(smem + 4 * RB))[tid] = ((const f32x4*)(ws + WS_Q_OFF))[tid];

    // stage s tile: f32 -> bf16 LDS (swizzled, rows 0..127 over the 64KB ring area) + sn2
    for (int i = 0; i < 32; ++i) {
        const int row = 4 * i + wid;
        const float4 v = ((const float4*)(s + (brow0 + row) * D_DIM))[lane];
        float ss = v.x * v.x + v.y * v.y + v.z * v.z + v.w * v.w;
        #pragma unroll
        for (int m = 1; m < 64; m <<= 1) ss += __shfl_xor(ss, m, 64);
        if (lane == 0) sn2[row] = ss;
        const int cb = (lane * 8) ^ ((row & 7) << 4);
        unsigned long long p = (unsigned long long)f2bf(v.x)
                             | ((unsigned long long)f2bf(v.y) << 16)
                             | ((unsigned long long)f2bf(v.z) << 32)
                             | ((unsigned long long)f2bf(v.w) << 48);
        *(unsigned long long*)(smem + row * 512 + cb) = p;
    }
    __syncthreads();

    // extract A fragments (registers for the whole K loop)
    s16x8 afrag[2][8];
    #pragma unroll
    for (int m = 0; m < 2; ++m)
        #pragma unroll
        for (int ks = 0; ks < 8; ++ks) {
            const int row = wid * 32 + m * 16 + lo;
            const int cb  = (ks * 64 + hi * 16) ^ ((row & 7) << 4);
            afrag[m][ks] = *(const s16x8*)(smem + row * 512 + cb);
        }
    float a1[2][4];
    #pragma unroll
    for (int m = 0; m < 2; ++m)
        #pragma unroll
        for (int r = 0; r < 4; ++r)
            a1[m][r] = -te * sn2[wid * 32 + m * 16 + hi * 4 + r];
    __syncthreads();   // ring area free; drains vmcnt to 0

    // lane-invariant split of the XOR swizzle:
    // byte = cl*512 + (ks*64 + hi*16) ^ ((lo&7)<<4)
    //      = [lo*512 + (hi*16 ^ (x&48)) + bit6(ks)] + (ks>>1)*128 + t*8192
    const int x    = (lo & 7) << 4;
    const int x64  = x & 64;
    const int vb   = lo * 512 + ((hi * 16) ^ (x & 48));
    const int ve   = vb + x64;          // even ks lane address
    const int vo   = vb + (64 ^ x64);   // odd ks lane address
    const unsigned char* qp = smem + 4 * RB + lo * 4;

#define STAGE(bufi, chunk) do {                                                          \
        const unsigned char* _g = ws + (chunk) * RB + wid * 1024 + (lane << 4);          \
        _Pragma("unroll")                                                                \
        for (int _i = 0; _i < 4; ++_i)                                                   \
            __builtin_amdgcn_global_load_lds(                                            \
                (const __attribute__((address_space(1))) unsigned int*)(_g + _i * 4096), \
                (__attribute__((address_space(3))) unsigned int*)                        \
                    (smem + (bufi) * RB + wid * 1024 + _i * 4096),                       \
                16, 0, 0);                                                               \
    } while (0)

    STAGE(0, 0);
    STAGE(1, 1);

    float rssum = 0.f;

#define BODY(cc, B, STG, VM) do {                                                        \
        if (STG) STAGE(((B) + 2) & 3, (cc) + 2);                                         \
        asm volatile("s_waitcnt vmcnt(" #VM ")" ::: "memory");                           \
        __builtin_amdgcn_s_barrier();                                                    \
        __builtin_amdgcn_sched_barrier(0);                                               \
        f32x4 acc[2][2] = {};                                                            \
        _Pragma("unroll")                                                                \
        for (int ks = 0; ks < 8; ++ks) {                                                 \
            const int base = ((ks & 1) ? vo : ve) + (ks >> 1) * 128 + (B) * RB;          \
            const s16x8 b0 = *(const s16x8*)(smem + base);                               \
            const s16x8 b1 = *(const s16x8*)(smem + base + 8192);                        \
            acc[0][0] = __builtin_amdgcn_mfma_f32_16x16x32_bf16(afrag[0][ks], b0, acc[0][0], 0, 0, 0); \
            acc[0][1] = __builtin_amdgcn_mfma_f32_16x16x32_bf16(afrag[0][ks], b1, acc[0][1], 0, 0, 0); \
            acc[1][0] = __builtin_amdgcn_mfma_f32_16x16x32_bf16(afrag[1][ks], b0, acc[1][0], 0, 0, 0); \
            acc[1][1] = __builtin_amdgcn_mfma_f32_16x16x32_bf16(afrag[1][ks], b1, acc[1][1], 0, 0, 0); \
        }                                                                                \
        const float q0 = *(const float*)(qp + (cc) * 128);                               \
        const float q1 = *(const float*)(qp + (cc) * 128 + 64);                          \
        _Pragma("unroll")                                                                \
        for (int m = 0; m < 2; ++m)                                                      \
            _Pragma("unroll")                                                            \
            for (int r = 0; r < 4; ++r) {                                                \
                const float g0 = fmaf(t2e, acc[m][0][r], q0 + a1[m][r]);                 \
                const float g1 = fmaf(t2e, acc[m][1][r], q1 + a1[m][r]);                 \
                float e0, e1;                                                            \
                asm("v_exp_f32 %0, %1" : "=v"(e0) : "v"(g0));                            \
                asm("v_exp_f32 %0, %1" : "=v"(e1) : "v"(g1));                            \
                rssum += e0;                                                             \
                rssum += e1;                                                             \
            }                                                                            \
    } while (0)

    for (int c3 = 0; c3 < 28; c3 += 4) {
        BODY(c3 + 0, 0, 1, 8);
        BODY(c3 + 1, 1, 1, 8);
        BODY(c3 + 2, 2, 1, 8);
        BODY(c3 + 3, 3, 1, 8);
    }
    BODY(28, 0, 1, 8);
    BODY(29, 1, 1, 8);
    BODY(30, 2, 0, 4);
    BODY(31, 3, 0, 0);
#undef BODY
#undef STAGE

    // block-wide exactness gate: w >= 0, so sum==0 <=> every w == 0
    const unsigned long long bal = __ballot(rssum != 0.f);
    if (lane == 0) nzflags[wid] = (bal != 0ULL) ? 1 : 0;
    __syncthreads();
    const int nzany = nzflags[0] | nzflags[1] | nzflags[2] | nzflags[3];

    if (nzany) {
        slow_path(s, centers, cw, means, temp, brow0, wid, lane, out);
    } else {
        const float4 z = {0.f, 0.f, 0.f, 0.f};
        float4* ob = (float4*)(out + (brow0 + wid * 32) * A_DIM);
        #pragma unroll
        for (int i = 0; i < 8; ++i) ob[lane + 64 * i] = z;
    }
}

__global__ void chol_kernel(const float* __restrict__ log_sigma, float* __restrict__ out2)
{
    const int i = blockIdx.x * 256 + threadIdx.x;   // < 4096
    const int r = i >> 6, c = i & 63;
    out2[i] = (r == c) ? __expf(log_sigma[r]) : 0.0f;
}

extern "C" void kernel_launch(void* const* d_in, const int* in_sizes, int n_in,
                              void* d_out, int out_size, void* d_ws, size_t ws_size,
                              hipStream_t stream)
{
    const float* s       = (const float*)d_in[0];
    const float* centers = (const float*)d_in[1];
    const float* cwts    = (const float*)d_in[2];
    const float* means   = (const float*)d_in[3];
    const float* lsig    = (const float*)d_in[4];
    const float* ltemp   = (const float*)d_in[5];
    float* out = (float*)d_out;
    unsigned char* ws = (unsigned char*)d_ws;   // needs 516KB

    prep_kernel<<<64, 256, 0, stream>>>(centers, cwts, ltemp, ws);
    fused_kernel<<<N_ROWS / 128, 256, 0, stream>>>(s, ws, means, centers, cwts, ltemp, out);
    chol_kernel<<<(A_DIM * A_DIM) / 256, 256, 0, stream>>>(lsig, out + (long)N_ROWS * A_DIM);
}